// Round 6
// baseline (614.962 us; speedup 1.0000x reference)
//
#include <hip/hip_runtime.h>

typedef _Float16 half8  __attribute__((ext_vector_type(8)));
typedef _Float16 half4  __attribute__((ext_vector_type(4)));
typedef float    float4v __attribute__((ext_vector_type(4)));

#define N_ROWS  65536   // 64*32*32
#define N_CODES 1024
#define DIM     256
#define BM      64              // rows per block
#define NB      (N_ROWS / BM)   // 1024 blocks

// ---- prep (r3/r4/r5-verified): one wave per code. ||e||^2 + f16 hi/lo split
// in MFMA B-frag order: frag b = nt*8+ks holds 1024 halves [hi 512][lo 512],
// slot = (quad*16+l15)*8+j -> code = nt*16+l15, k = ks*32+quad*8+j.
__global__ __launch_bounds__(64)
void vq_prep(const float* __restrict__ emb, float* __restrict__ e_norm,
             _Float16* __restrict__ e_frag) {
    const int c = blockIdx.x, lane = threadIdx.x;
    const int l15 = c & 15, nt = c >> 4;
    float4v v = ((const float4v*)(emb + (size_t)c * DIM))[lane];
    half4 h, l;
    float ss = 0.f;
    #pragma unroll
    for (int j = 0; j < 4; ++j) {
        float x = v[j];
        ss += x * x;
        _Float16 hh = (_Float16)x;
        h[j] = hh;
        l[j] = (_Float16)(x - (float)hh);
    }
    const int ks = lane >> 3, q = (lane >> 1) & 3, jb = (lane & 1) * 4;
    _Float16* p = e_frag + ((size_t)(nt * 8 + ks)) * 1024 + (q * 16 + l15) * 8 + jb;
    *(half4*)p = h;
    *(half4*)(p + 512) = l;
    #pragma unroll
    for (int m = 32; m >= 1; m >>= 1) ss += __shfl_xor(ss, m, 64);
    if (lane == 0) e_norm[c] = ss;
}

// ---- main: 512 thr (8 waves), block = 64 rows x ALL 1024 codes.
// A-tile (64 rows, full K, hi/lo) converted once into 64 KB LDS; B-frags
// streamed from 1 MB L2-resident e_frag (each code read once per block).
// Wave = 64 rows x 128 codes (2 chunks of 64; acc=64 AGPR). LDS ~68.5 KB ->
// 2 blocks/CU -> 4 waves/SIMD; co-resident blocks hide each other's staging.
// Full argmin in-block -> idx write + fused gather (no partials/reduce).
__global__ __launch_bounds__(512, 4)
void vq_main(const float* __restrict__ z,
             const _Float16* __restrict__ e_frag,
             const float* __restrict__ e_norm,
             const float* __restrict__ emb,
             float* __restrict__ zq,
             float* __restrict__ idxf,
             int fused) {
    __shared__ alignas(16) _Float16 sA[BM * DIM * 2];  // 64 KB, A-frag order
    __shared__ float  s_nrm[N_CODES];                  // 4 KB
    __shared__ float2 s_best[BM][8];                   // 4 KB
    __shared__ int    s_idx[BM];

    const int t = threadIdx.x;
    const int w = t >> 6, lane = t & 63, quad = lane >> 4, l15 = lane & 15;
    const int rowbase = blockIdx.x * BM;

    s_nrm[t] = e_norm[t];
    s_nrm[t + 512] = e_norm[t + 512];

    // ---- stage A: thread t handles (row = t>>3, ks = t&7): 32 consecutive
    // floats -> hi/lo -> frag g = mt*8+ks at g*1024 + (quad*16+l15)*8 (+512 lo)
    {
        const int row = t >> 3, ks = t & 7;
        const int mt = row >> 4, l15r = row & 15;
        const float4v* src = (const float4v*)(z + ((size_t)(rowbase + row)) * DIM + ks * 32);
        float4v v[8];
        #pragma unroll
        for (int i = 0; i < 8; ++i) v[i] = src[i];
        _Float16* dst = sA + (size_t)(mt * 8 + ks) * 1024 + l15r * 8;
        #pragma unroll
        for (int q = 0; q < 4; ++q) {
            half8 h, l;
            #pragma unroll
            for (int j = 0; j < 4; ++j) {
                float x = v[2 * q][j];     _Float16 hx = (_Float16)x;
                h[j] = hx;                 l[j] = (_Float16)(x - (float)hx);
                float y = v[2 * q + 1][j]; _Float16 hy = (_Float16)y;
                h[4 + j] = hy;             l[4 + j] = (_Float16)(y - (float)hy);
            }
            *(half8*)(dst + q * 128) = h;          // (q*16)*8 halves
            *(half8*)(dst + q * 128 + 512) = l;
        }
    }
    __syncthreads();   // the only pre-compute barrier

    float bs[4][4];
    int   bi[4][4];
    #pragma unroll
    for (int mt = 0; mt < 4; ++mt)
        #pragma unroll
        for (int r = 0; r < 4; ++r) { bs[mt][r] = 3.4e38f; bi[mt][r] = 0; }

    for (int chunk = 0; chunk < 2; ++chunk) {
        float4v acc[4][4] = {};

        #pragma unroll
        for (int ks = 0; ks < 8; ++ks) {
            half8 ah[4], al[4];
            #pragma unroll
            for (int mt = 0; mt < 4; ++mt) {
                const _Float16* ap = sA + (size_t)(mt * 8 + ks) * 1024 + lane * 8;
                ah[mt] = *(const half8*)ap;
                al[mt] = *(const half8*)(ap + 512);
            }
            #pragma unroll
            for (int ntl = 0; ntl < 4; ++ntl) {
                const int nt = w * 8 + chunk * 4 + ntl;   // global 16-code group
                const _Float16* bp = e_frag + ((size_t)nt * 8 + ks) * 1024 + lane * 8;
                half8 bh = *(const half8*)bp;
                half8 bl = *(const half8*)(bp + 512);
                // per-acc order hh,hl,lh — bit-identical to r2-r5
                #pragma unroll
                for (int mt = 0; mt < 4; ++mt)
                    acc[mt][ntl] = __builtin_amdgcn_mfma_f32_16x16x32_f16(ah[mt], bh, acc[mt][ntl], 0, 0, 0);
                #pragma unroll
                for (int mt = 0; mt < 4; ++mt)
                    acc[mt][ntl] = __builtin_amdgcn_mfma_f32_16x16x32_f16(ah[mt], bl, acc[mt][ntl], 0, 0, 0);
                #pragma unroll
                for (int mt = 0; mt < 4; ++mt)
                    acc[mt][ntl] = __builtin_amdgcn_mfma_f32_16x16x32_f16(al[mt], bh, acc[mt][ntl], 0, 0, 0);
            }
        }

        // merge chunk into running best (codes ascend over chunk,ntl: strict <
        // keeps lowest index; C/D layout: col=l15, row=quad*4+r)
        #pragma unroll
        for (int ntl = 0; ntl < 4; ++ntl) {
            const int code = w * 128 + chunk * 64 + ntl * 16 + l15;
            const float nrm = s_nrm[code];
            #pragma unroll
            for (int mt = 0; mt < 4; ++mt)
                #pragma unroll
                for (int r = 0; r < 4; ++r) {
                    float s = nrm - 2.0f * acc[mt][ntl][r];
                    if (s < bs[mt][r]) { bs[mt][r] = s; bi[mt][r] = code; }
                }
        }
    }

    // 16-lane reduce (same-row lanes = the 16 l15 values)
    #pragma unroll
    for (int m = 1; m < 16; m <<= 1)
        #pragma unroll
        for (int mt = 0; mt < 4; ++mt)
            #pragma unroll
            for (int r = 0; r < 4; ++r) {
                float s2 = __shfl_xor(bs[mt][r], m, 64);
                int   i2 = __shfl_xor(bi[mt][r], m, 64);
                if (s2 < bs[mt][r] || (s2 == bs[mt][r] && i2 < bi[mt][r])) {
                    bs[mt][r] = s2; bi[mt][r] = i2;
                }
            }
    if (l15 == 0) {
        #pragma unroll
        for (int mt = 0; mt < 4; ++mt)
            #pragma unroll
            for (int r = 0; r < 4; ++r) {
                const int row = mt * 16 + quad * 4 + r;
                float2 pr; pr.x = bs[mt][r]; pr.y = (float)bi[mt][r];
                s_best[row][w] = pr;
            }
    }
    __syncthreads();

    // block reduce over the 8 wave slots; write indices
    if (t < BM) {
        float2 p0 = s_best[t][0];
        float bsv = p0.x, biv = p0.y;
        #pragma unroll
        for (int s = 1; s < 8; ++s) {
            float2 pv = s_best[t][s];
            if (pv.x < bsv || (pv.x == bsv && pv.y < biv)) { bsv = pv.x; biv = pv.y; }
        }
        s_idx[t] = (int)biv;
        idxf[rowbase + t] = biv;
    }

    if (!fused) return;
    __syncthreads();

    // fused gather: 8 threads/row, 8 float4 each (emb rows are L2/L3-hot)
    {
        const int row = t >> 3, part = t & 7;
        const int code = s_idx[row];
        const float4* eb = (const float4*)(emb + (size_t)code * DIM);
        float4* oq = (float4*)(zq + (size_t)(rowbase + row) * DIM);
        #pragma unroll
        for (int i = 0; i < 8; ++i) oq[part + i * 8] = eb[part + i * 8];
    }
}

// ---- fallback gather (only if ws too small for e_frag): wave per row ----
__global__ __launch_bounds__(256)
void vq_gather(const float* __restrict__ emb,
               const float* __restrict__ idxf,
               float* __restrict__ zq) {
    const int tid  = blockIdx.x * 256 + threadIdx.x;
    const int r    = tid >> 6;
    const int lane = tid & 63;
    const int idx  = (int)idxf[r];
    const float4* ep = (const float4*)(emb + (size_t)idx * DIM);
    ((float4*)(zq + (size_t)r * DIM))[lane] = ep[lane];
}

extern "C" void kernel_launch(void* const* d_in, const int* in_sizes, int n_in,
                              void* d_out, int out_size, void* d_ws, size_t ws_size,
                              hipStream_t stream) {
    const float* z   = (const float*)d_in[0];   // (64,32,32,256) fp32
    const float* emb = (const float*)d_in[1];   // (1024,256) fp32

    float* zq   = (float*)d_out;                        // output 0: 16,777,216 f
    float* idxf = zq + (size_t)N_ROWS * DIM;            // output 1: 65,536 f

    const size_t efrag_b = (size_t)N_CODES * DIM * 2 * sizeof(_Float16);   // 1 MiB
    const size_t need = 4096 + efrag_b;

    // Scratch: prefer ws. Fallback: head of the zq region (main then writes
    // idx only; separate gather overwrites zq afterwards).
    char* base = (ws_size >= need) ? (char*)d_ws : (char*)zq;
    const int fused = (ws_size >= need);
    float*    e_norm = (float*)base;
    _Float16* e_frag = (_Float16*)(base + 4096);

    vq_prep<<<N_CODES, 64, 0, stream>>>(emb, e_norm, e_frag);
    vq_main<<<NB, 512, 0, stream>>>(z, e_frag, e_norm, emb, zq, idxf, fused);
    if (!fused)
        vq_gather<<<(N_ROWS * 64) / 256, 256, 0, stream>>>(emb, idxf, zq);
}